// Round 10
// baseline (155.952 us; speedup 1.0000x reference)
//
#include <hip/hip_runtime.h>

// pred/target (4,4,64,128,128) fp32 -> 16 volumes of 64x128x128.
#define NB 16
#define DD 64
#define HH 128
#define WW 128
#define HW (HH * WW)

constexpr int CD = 2;                  // output planes per tile
constexpr int TH = 8;                  // output rows per block
constexpr int LZ = CD + 2;             // 4 input planes per tile
constexpr int LY = TH + 2;             // 10 input rows
constexpr int PL = LY * WW;            // LDS plane stride (floats) = 1280
constexpr int NPOS = LZ * LY * (WW / 4); // 1280 float4 slots per tile
constexpr int SLOTS = NPOS / 256;      // 5 slots per thread
constexpr int NT = 8;                  // tiles per block along d (8*2 = 16 planes)
constexpr float INV_COUNT = 1.0f / 50331648.0f; // 1/(3*16*64*128*128)

__global__ void zero_out_kernel(float* out) {
    if (threadIdx.x == 0 && blockIdx.x == 0) out[0] = 0.0f;
}

__global__ __launch_bounds__(256) void sobel_l1_kernel(
    const float* __restrict__ pred,
    const float* __restrict__ target,
    float* __restrict__ out)
{
    // 2 x 20 KB double buffer = 40960 B; 4 blocks/CU = 163840 B = full LDS pool.
    __shared__ float t[2][LZ * PL];

    const int tid = threadIdx.x;
    int b = blockIdx.x;                // 1024 blocks: 16 bh x 4 quarter x 16 bn
    const int bh = b & 15; b >>= 4;
    const int qt = b & 3;  b >>= 2;
    const int bn = b;

    const int h0 = bh * TH;
    const int dbase = qt * (NT * CD);  // 0, 16, 32, 48
    const size_t nbase = (size_t)bn * (size_t)(DD * HW);

    // ---- per-slot constants (5 float4 slots per thread per tile) ----
    int  soff[SLOTS];   // clamped row offset + 4*q4 (elements within a plane)
    int  sz[SLOTS];     // z in 0..3
    bool sokh[SLOTS];   // h in range
#pragma unroll
    for (int k = 0; k < SLOTS; ++k) {
        const int i  = k * 256 + tid;  // 0..1279
        const int q4 = i & 31;
        const int ry = i >> 5;         // 0..39
        const int z  = ry / LY;
        const int y  = ry - z * LY;
        const int gh = h0 - 1 + y;
        sokh[k] = (unsigned)gh < HH;
        soff[k] = min(max(gh, 0), HH - 1) * WW + 4 * q4;
        sz[k]   = z;
    }

    float4 sp[SLOTS], sq[SLOTS];       // raw staging (subtract deferred to store)

    auto load_tile = [&](int tau) {
        const int d0 = dbase + tau * CD;
#pragma unroll
        for (int k = 0; k < SLOTS; ++k) {
            const int gd  = d0 - 1 + sz[k];
            const int gdc = min(max(gd, 0), DD - 1);
            const size_t idx = nbase + (size_t)gdc * HW + soff[k];
            sp[k] = *(const float4*)(pred + idx);
            sq[k] = *(const float4*)(target + idx);
        }
    };

    auto store_tile = [&](int tau, float* B) {
        const int d0 = dbase + tau * CD;
#pragma unroll
        for (int k = 0; k < SLOTS; ++k) {
            const int gd = d0 - 1 + sz[k];
            const float m = (sokh[k] && (unsigned)gd < DD) ? 1.0f : 0.0f;
            const int i = k * 256 + tid;
            const float4 v = float4{(sp[k].x - sq[k].x) * m,
                                    (sp[k].y - sq[k].y) * m,
                                    (sp[k].z - sq[k].z) * m,
                                    (sp[k].w - sq[k].w) * m};
            *(float4*)&B[4 * i] = v;
        }
    };

    const int tc = tid & 31;           // w-quad
    const int lh = tid >> 5;           // output row in tile

    auto compute_tile = [&](const float* B, float& acc) {
        // Per-plane partials: A = s(h)s(w)v, Bh = d(h)s(w)v, Bw = s(h)d(w)v.
        auto plane_l = [&](int z, float4& A_, float4& Bh_, float4& Bw_) {
            float4 rs[3], rdw[3];
#pragma unroll
            for (int r = 0; r < 3; ++r) {
                const float4 v = *(const float4*)&B[z * PL + (lh + r) * WW + 4 * tc];
                float lm = __shfl_up(v.w, 1, 32);
                float rp = __shfl_down(v.x, 1, 32);
                if (tc == 0)  lm = 0.f;
                if (tc == 31) rp = 0.f;
                rs[r]  = float4{lm  + 2.f * v.x + v.y,
                                v.x + 2.f * v.y + v.z,
                                v.y + 2.f * v.z + v.w,
                                v.z + 2.f * v.w + rp};
                rdw[r] = float4{v.y - lm, v.z - v.x, v.w - v.y, rp - v.z};
            }
            A_  = float4{rs[0].x + 2.f * rs[1].x + rs[2].x,
                         rs[0].y + 2.f * rs[1].y + rs[2].y,
                         rs[0].z + 2.f * rs[1].z + rs[2].z,
                         rs[0].w + 2.f * rs[1].w + rs[2].w};
            Bh_ = float4{rs[2].x - rs[0].x, rs[2].y - rs[0].y,
                         rs[2].z - rs[0].z, rs[2].w - rs[0].w};
            Bw_ = float4{rdw[0].x + 2.f * rdw[1].x + rdw[2].x,
                         rdw[0].y + 2.f * rdw[1].y + rdw[2].y,
                         rdw[0].z + 2.f * rdw[1].z + rdw[2].z,
                         rdw[0].w + 2.f * rdw[1].w + rdw[2].w};
        };

        float4 rA[3], rBh[3], rBw[3];
        plane_l(0, rA[0], rBh[0], rBw[0]);
        plane_l(1, rA[1], rBh[1], rBw[1]);
#pragma unroll
        for (int ld = 0; ld < CD; ++ld) {
            const int s0 = ld % 3, s1 = (ld + 1) % 3, s2 = (ld + 2) % 3;
            plane_l(ld + 2, rA[s2], rBh[s2], rBw[s2]);
            const float4 a0 = rA[s0],  a2 = rA[s2];
            const float4 b0 = rBh[s0], b1 = rBh[s1], b2 = rBh[s2];
            const float4 c0 = rBw[s0], c1 = rBw[s1], c2 = rBw[s2];
            acc += fabsf(a2.x - a0.x) + fabsf(a2.y - a0.y)
                 + fabsf(a2.z - a0.z) + fabsf(a2.w - a0.w);
            acc += fabsf(b0.x + 2.f * b1.x + b2.x) + fabsf(b0.y + 2.f * b1.y + b2.y)
                 + fabsf(b0.z + 2.f * b1.z + b2.z) + fabsf(b0.w + 2.f * b1.w + b2.w);
            acc += fabsf(c0.x + 2.f * c1.x + c2.x) + fabsf(c0.y + 2.f * c1.y + c2.y)
                 + fabsf(c0.z + 2.f * c1.z + c2.z) + fabsf(c0.w + 2.f * c1.w + c2.w);
        }
    };

    // ---- software-pipelined persistent loop over NT tiles ----
    float acc = 0.0f;
    load_tile(0);
    store_tile(0, t[0]);
    __syncthreads();
    for (int tau = 0; tau < NT; ++tau) {
        if (tau + 1 < NT) load_tile(tau + 1);      // in flight during compute
        compute_tile(t[tau & 1], acc);
        if (tau + 1 < NT) store_tile(tau + 1, t[(tau + 1) & 1]);
        __syncthreads();   // publishes tile tau+1; orders reads vs next store
    }

    // ---- block reduction (reuse t[0] as wave-sum scratch) ----
#pragma unroll
    for (int off = 32; off > 0; off >>= 1)
        acc += __shfl_down(acc, off, 64);
    if ((tid & 63) == 0) t[0][tid >> 6] = acc;
    __syncthreads();
    if (tid == 0) {
        const float s = t[0][0] + t[0][1] + t[0][2] + t[0][3];
        atomicAdd(out, s * INV_COUNT);
    }
}

extern "C" void kernel_launch(void* const* d_in, const int* in_sizes, int n_in,
                              void* d_out, int out_size, void* d_ws, size_t ws_size,
                              hipStream_t stream) {
    const float* pred   = (const float*)d_in[0];
    const float* target = (const float*)d_in[1];
    float* out = (float*)d_out;

    zero_out_kernel<<<1, 64, 0, stream>>>(out);

    // 16 volumes * 4 d-quarters * 16 h-tiles = 1024 blocks -> 4 blocks/CU
    const int nblocks = NB * 4 * (HH / TH);
    sobel_l1_kernel<<<nblocks, 256, 0, stream>>>(pred, target, out);
}